// Round 1
// baseline (110.647 us; speedup 1.0000x reference)
//
#include <hip/hip_runtime.h>
#include <math.h>

#define B_N  4
#define CIN  64
#define COUT 64
#define H_N  128
#define W_N  128

typedef _Float16 half8 __attribute__((ext_vector_type(8)));
typedef float    f32x4 __attribute__((ext_vector_type(4)));

#define KTOT   1728              // 27 groups (t*3+h) * 64 c
#define NSTEP  54                // KTOT / 32
#define WA_BYTES ((size_t)NSTEP * 4 * 64 * 8 * 2)   // 221184 B

// ---- pack weights (3,Cout,Cin,3,3) fp32 -> f16 in MFMA A-fragment order ----
// A-fragment for K-step s, m-tile mt, lane l: 8 f16 = A[m=mt*16+(l&15)][k=s*32+(l>>4)*8+j]
// k -> (t,h,c): g=k>>6, c=k&63, t=g/3, h=g%3
__global__ void wprep(const float* __restrict__ w, _Float16* __restrict__ wa) {
    int idx = blockIdx.x * 256 + threadIdx.x;        // (s, mt, lane)
    if (idx >= NSTEP * 4 * 64) return;
    int lane = idx & 63;
    int mt   = (idx >> 6) & 3;
    int s    = idx >> 8;
    int m    = mt * 16 + (lane & 15);
    int kl0  = (lane >> 4) * 8;
    _Float16 v[8];
#pragma unroll
    for (int j = 0; j < 8; ++j) {
        int k = s * 32 + kl0 + j;
        int g = k >> 6;
        int c = k & 63;
        int t = g / 3;
        int h = g % 3;
        v[j] = (_Float16)w[(((size_t)(h * COUT) + m) * CIN + c) * 9 + t];
    }
    *(int4*)&wa[(size_t)idx * 8] = *(int4*)v;
}

// R4: XOR chunk-swizzle replaces the +8 pad. Line = 64 halfs (128 B) per (dy,x);
// 16-B chunk c of line xi lives at halfs offset xi*64 + ((c ^ (xi&7))*8).
// Reads and writes are both 2-way bank aliased (free); LDS 56160 -> 49920 B
// -> 3 blocks/CU (12 waves) instead of 2.
#define XS_LINE 64
#define XS_ROW  (130 * XS_LINE)          // 8320 halfs per dy-plane

// Block = one (b,y): 128 pixels x 64 Cout. 4 waves x 32 pixels.
// Per-tap __syncthreads() keeps waves lockstepped so the tap's A-tile is
// shared in L1 (R3 lesson). A-fragments batched per-h (8 frags, 32 VGPR)
// instead of per-tap (24 frags, 96 VGPR) so 3 waves/SIMD fits.
__global__ __launch_bounds__(256, 3)
void conv_mfma(const float* __restrict__ inp, const float* __restrict__ depth,
               const _Float16* __restrict__ wa, const float* __restrict__ bias,
               const int* __restrict__ fptr, float* __restrict__ out) {
    __shared__ _Float16 Xs[3 * XS_ROW];              // 49920 B

    int bid  = blockIdx.x;
    int y    = bid & (H_N - 1);
    int b    = bid >> 7;
    int tid  = threadIdx.x;
    int lane = tid & 63;
    int wid  = tid >> 6;
    int p0   = wid * 32;
    int ln15 = lane & 15;
    int quad = lane >> 4;

    // ---- stage 3 input rows (dy=-1,0,1), transposed to [x][c], f16, swizzled ----
    {
        int x     = tid & 127;
        int chalf = tid >> 7;                        // c in [chalf*32, chalf*32+32)
        int xi    = x + 1;
        int key   = xi & 7;
        for (int dyi = 0; dyi < 3; ++dyi) {
            int yy = y + dyi - 1;
            _Float16 buf[32];
            if (yy >= 0 && yy < H_N) {
                const float* src = inp + (((size_t)b * CIN + chalf * 32) * H_N + yy) * W_N + x;
#pragma unroll
                for (int cc = 0; cc < 32; ++cc)
                    buf[cc] = (_Float16)src[(size_t)cc * H_N * W_N];
            } else {
#pragma unroll
                for (int cc = 0; cc < 32; ++cc) buf[cc] = (_Float16)0.f;
            }
            _Float16* dst = &Xs[dyi * XS_ROW + xi * XS_LINE];
#pragma unroll
            for (int k = 0; k < 4; ++k)
                *(int4*)&dst[((chalf * 4 + k) ^ key) * 8] = *(int4*)&buf[k * 8];
        }
        // zero pad lines at x=-1 (line 0) and x=128 (line 129): zero all 8 chunks,
        // so the swizzle is irrelevant here.
        if (tid < 48) {
            int dyi = tid / 16;
            int rem = tid % 16;
            int xz  = (rem >= 8) ? 129 : 0;
            int k8  = rem & 7;
            int4 z  = {0, 0, 0, 0};
            *(int4*)&Xs[dyi * XS_ROW + xz * XS_LINE + k8 * 8] = z;
        }
    }

    // ---- per-lane h-selection packs (exact fp64, identical to R1-R3) ----
    double fd = (double)(*fptr);
    unsigned hpk[2];
#pragma unroll
    for (int nt = 0; nt < 2; ++nt) {
        int x = p0 + nt * 16 + ln15;
        float d0f = depth[((size_t)b * H_N + y) * W_N + x];
        double dd = (double)d0f;
        double s0 = dd / fd;
        unsigned pk = 0;
        for (int t = 0; t < 9; ++t) {
            int dy = t / 3 - 1, dx = t % 3 - 1;
            int yy = y + dy, xx = x + dx;
            float dwf = (yy >= 0 && yy < H_N && xx >= 0 && xx < W_N)
                        ? depth[((size_t)b * H_N + yy) * W_N + xx] : 0.f;
            int h = -1;
            if (s0 > 0.0) {
                double u  = ((double)dwf - dd) / s0 + 1.5;
                double uf = floor(u);
                if (uf >= 0.0 && uf <= 2.0) h = (int)uf;
            }
            pk |= (unsigned)(h + 1) << (2 * t);
        }
        hpk[nt] = pk;
    }

    __syncthreads();

    // ---- MFMA main loop: 9 taps x (3 h x 2 kk) ----
    f32x4 acc[4][2];
#pragma unroll
    for (int mt = 0; mt < 4; ++mt)
#pragma unroll
        for (int nt = 0; nt < 2; ++nt) acc[mt][nt] = (f32x4){0.f, 0.f, 0.f, 0.f};

    const half8* wa8 = (const half8*)wa;   // frag index: (s*4 + mt)*64 + lane

    for (int t = 0; t < 9; ++t) {
        int dyi = t / 3;
        int dx  = t % 3 - 1;
        int xs0 = p0 + ln15 + dx + 1;                // LDS line for nt=0; nt=1 is +16 (same key)
        int key = xs0 & 7;
        int base0 = dyi * XS_ROW + xs0 * XS_LINE;
        int base1 = base0 + 16 * XS_LINE;
        int offk0 = ((quad + 0) ^ key) * 8;          // chunk kk=0: quad
        int offk1 = ((quad + 4) ^ key) * 8;          // chunk kk=1: quad+4
        int hb0 = (hpk[0] >> (2 * t)) & 3;
        int hb1 = (hpk[1] >> (2 * t)) & 3;

        // 4 distinct B vectors for this tap (h-invariant; was 12 redundant reads)
        half8 b00 = *(const half8*)&Xs[base0 + offk0];   // nt=0, kk=0
        half8 b01 = *(const half8*)&Xs[base0 + offk1];   // nt=0, kk=1
        half8 b10 = *(const half8*)&Xs[base1 + offk0];   // nt=1, kk=0
        half8 b11 = *(const half8*)&Xs[base1 + offk1];   // nt=1, kk=1

        const half8* baseA = wa8 + ((size_t)t * 6 * 4) * 64 + lane;

#pragma unroll
        for (int h = 0; h < 3; ++h) {
            // batch-load this h's A-fragments: 2 K-steps x 4 m-tiles (32 VGPR)
            half8 A0[4], A1[4];
#pragma unroll
            for (int mt = 0; mt < 4; ++mt) {
                A0[mt] = baseA[(h * 8 + 0 + mt) * 64];
                A1[mt] = baseA[(h * 8 + 4 + mt) * 64];
            }
            bool m0 = (hb0 == h + 1);
            bool m1 = (hb1 == h + 1);
            half8 z  = {(_Float16)0.f, (_Float16)0.f, (_Float16)0.f, (_Float16)0.f,
                        (_Float16)0.f, (_Float16)0.f, (_Float16)0.f, (_Float16)0.f};
            // accumulation order preserved vs R3: (h, kk, mt, nt)
            {
                half8 c0 = m0 ? b00 : z;
                half8 c1 = m1 ? b10 : z;
#pragma unroll
                for (int mt = 0; mt < 4; ++mt) {
                    acc[mt][0] = __builtin_amdgcn_mfma_f32_16x16x32_f16(A0[mt], c0, acc[mt][0], 0, 0, 0);
                    acc[mt][1] = __builtin_amdgcn_mfma_f32_16x16x32_f16(A0[mt], c1, acc[mt][1], 0, 0, 0);
                }
            }
            {
                half8 c0 = m0 ? b01 : z;
                half8 c1 = m1 ? b11 : z;
#pragma unroll
                for (int mt = 0; mt < 4; ++mt) {
                    acc[mt][0] = __builtin_amdgcn_mfma_f32_16x16x32_f16(A1[mt], c0, acc[mt][0], 0, 0, 0);
                    acc[mt][1] = __builtin_amdgcn_mfma_f32_16x16x32_f16(A1[mt], c1, acc[mt][1], 0, 0, 0);
                }
            }
        }
        __syncthreads();   // lockstep the block's waves -> shared L1 A-tile
    }

    // ---- epilogue: D[m=o: quad*4+r][n=pixel: lane&15] + bias ----
#pragma unroll
    for (int mt = 0; mt < 4; ++mt) {
#pragma unroll
        for (int nt = 0; nt < 2; ++nt) {
            int x = p0 + nt * 16 + ln15;
#pragma unroll
            for (int r = 0; r < 4; ++r) {
                int o = mt * 16 + quad * 4 + r;
                out[(((size_t)b * COUT + o) * H_N + y) * W_N + x] = acc[mt][nt][r] + bias[o];
            }
        }
    }
}

// ---- fallback scalar kernel (used only if ws too small) ----
__global__ __launch_bounds__(256)
void conv25d(const float* __restrict__ inp, const float* __restrict__ depth,
             const float* __restrict__ wsrc, const float* __restrict__ bias,
             const int* __restrict__ fptr, float* __restrict__ out) {
    int bid = blockIdx.x;
    int xt  = bid & 3;
    int y   = (bid >> 2) & (H_N - 1);
    int b   = bid >> 9;
    int o   = threadIdx.x & 63;
    int q   = threadIdx.x >> 6;
    int x0  = xt * 32 + q * 8;
    double fd = (double)(*fptr);
    float acc[8];
    float bv = bias[o];
#pragma unroll
    for (int i = 0; i < 8; ++i) acc[i] = bv;
    const float* dcen = depth + ((size_t)b * H_N + y) * W_N;
    float d0[8];
#pragma unroll
    for (int i = 0; i < 8; ++i) d0[i] = dcen[x0 + i];
    for (int t = 0; t < 9; ++t) {
        int dy = t / 3 - 1, dx = t % 3 - 1;
        int yy = y + dy;
        if (yy < 0 || yy >= H_N) continue;
        const float* drow = depth + ((size_t)b * H_N + yy) * W_N;
        int hsel[8];
#pragma unroll
        for (int i = 0; i < 8; ++i) {
            int xx = x0 + i + dx;
            int h = -1;
            if (xx >= 0 && xx < W_N) {
                double dd = (double)d0[i];
                double s0 = dd / fd;
                if (s0 > 0.0) {
                    double u = ((double)drow[xx] - dd) / s0 + 1.5;
                    double uf = floor(u);
                    if (uf >= 0.0 && uf <= 2.0) h = (int)uf;
                }
            }
            hsel[i] = h;
        }
        const float* irow = inp + ((size_t)b * CIN * H_N + yy) * W_N;
        for (int c = 0; c < CIN; ++c) {
            const float* wb = wsrc + ((size_t)o * CIN + c) * 9 + t;
            float w0 = wb[0], w1 = wb[(size_t)COUT * CIN * 9], w2 = wb[2 * (size_t)COUT * CIN * 9];
            const float* ir = irow + (size_t)c * H_N * W_N;
#pragma unroll
            for (int i = 0; i < 8; ++i) {
                int h = hsel[i];
                if (h >= 0) {
                    float wv = (h == 0) ? w0 : ((h == 1) ? w1 : w2);
                    acc[i] = fmaf(ir[x0 + i + dx], wv, acc[i]);
                }
            }
        }
    }
    float* orow = out + (((size_t)b * COUT + o) * H_N + y) * W_N;
#pragma unroll
    for (int i = 0; i < 8; ++i) orow[x0 + i] = acc[i];
}

extern "C" void kernel_launch(void* const* d_in, const int* in_sizes, int n_in,
                              void* d_out, int out_size, void* d_ws, size_t ws_size,
                              hipStream_t stream) {
    const float* inp   = (const float*)d_in[0];
    const float* depth = (const float*)d_in[1];
    const float* w     = (const float*)d_in[2];
    const float* bias  = (const float*)d_in[3];
    const int*   f     = (const int*)d_in[4];
    float* out = (float*)d_out;

    if (ws_size >= WA_BYTES) {
        _Float16* wa = (_Float16*)d_ws;
        wprep<<<NSTEP, 256, 0, stream>>>(w, wa);
        conv_mfma<<<B_N * H_N, 256, 0, stream>>>(inp, depth, wa, bias, f, out);
    } else {
        conv25d<<<B_N * H_N * (W_N / 32), 256, 0, stream>>>(inp, depth, w, bias, f, out);
    }
}

// Round 2
// 103.876 us; speedup vs baseline: 1.0652x; 1.0652x over previous
//
#include <hip/hip_runtime.h>
#include <math.h>

#define B_N  4
#define CIN  64
#define COUT 64
#define H_N  128
#define W_N  128

typedef _Float16 half8 __attribute__((ext_vector_type(8)));
typedef float    f32x4 __attribute__((ext_vector_type(4)));

#define KTOT   1728              // 27 groups (t*3+h) * 64 c
#define NSTEP  54                // KTOT / 32
#define WA_BYTES ((size_t)NSTEP * 4 * 64 * 8 * 2)   // 221184 B

// ---- pack weights (3,Cout,Cin,3,3) fp32 -> f16 in MFMA A-fragment order ----
// A-fragment for K-step s, m-tile mt, lane l: 8 f16 = A[m=mt*16+(l&15)][k=s*32+(l>>4)*8+j]
// k -> (t,h,c): g=k>>6, c=k&63, t=g/3, h=g%3
__global__ void wprep(const float* __restrict__ w, _Float16* __restrict__ wa) {
    int idx = blockIdx.x * 256 + threadIdx.x;        // (s, mt, lane)
    if (idx >= NSTEP * 4 * 64) return;
    int lane = idx & 63;
    int mt   = (idx >> 6) & 3;
    int s    = idx >> 8;
    int m    = mt * 16 + (lane & 15);
    int kl0  = (lane >> 4) * 8;
    _Float16 v[8];
#pragma unroll
    for (int j = 0; j < 8; ++j) {
        int k = s * 32 + kl0 + j;
        int g = k >> 6;
        int c = k & 63;
        int t = g / 3;
        int h = g % 3;
        v[j] = (_Float16)w[(((size_t)(h * COUT) + m) * CIN + c) * 9 + t];
    }
    *(int4*)&wa[(size_t)idx * 8] = *(int4*)v;
}

// XOR chunk-swizzle LDS layout (R4): line = 64 halfs (128 B) per (dy,x);
// logical 16-B chunk lc of line xi lives at halfs offset xi*64 + ((lc ^ (xi&7))*8).
// Reads and writes both schedule conflict-free. LDS = 49920 B.
#define XS_LINE 64
#define XS_ROW  (130 * XS_LINE)          // 8320 halfs per dy-plane

// R5: back to per-tap 24-frag A batches (R3's 9 latency exposures, not R4's 27),
// with software pipelining: tap t+1's A-loads + B ds_reads issue BEFORE the
// per-tap barrier so they fly during the barrier wait. h-pack divides cut
// 20 -> 2 per thread. Staging loads batched (1 latency exposure, not 3).
__global__ __launch_bounds__(256, 2)
void conv_mfma(const float* __restrict__ inp, const float* __restrict__ depth,
               const _Float16* __restrict__ wa, const float* __restrict__ bias,
               const int* __restrict__ fptr, float* __restrict__ out) {
    __shared__ _Float16 Xs[3 * XS_ROW];              // 49920 B

    int bid  = blockIdx.x;
    int y    = bid & (H_N - 1);
    int b    = bid >> 7;
    int tid  = threadIdx.x;
    int lane = tid & 63;
    int wid  = tid >> 6;
    int p0   = wid * 32;
    int ln15 = lane & 15;
    int quad = lane >> 4;

    // ---- stage 3 input rows (dy=-1,0,1), transposed to [x][c], f16, swizzled ----
    // All 96 global loads issued as one batch (max MLP), then convert+write.
    {
        int x     = tid & 127;
        int chalf = tid >> 7;                        // c in [chalf*32, chalf*32+32)
        int xi    = x + 1;
        int key   = xi & 7;
        float fbuf[3][32];
#pragma unroll
        for (int dyi = 0; dyi < 3; ++dyi) {
            int yy = y + dyi - 1;
            if (yy >= 0 && yy < H_N) {
                const float* src = inp + (((size_t)b * CIN + chalf * 32) * H_N + yy) * W_N + x;
#pragma unroll
                for (int cc = 0; cc < 32; ++cc)
                    fbuf[dyi][cc] = src[(size_t)cc * H_N * W_N];
            } else {
#pragma unroll
                for (int cc = 0; cc < 32; ++cc) fbuf[dyi][cc] = 0.f;
            }
        }
#pragma unroll
        for (int dyi = 0; dyi < 3; ++dyi) {
            _Float16 hb[32];
#pragma unroll
            for (int cc = 0; cc < 32; ++cc) hb[cc] = (_Float16)fbuf[dyi][cc];
            _Float16* dst = &Xs[dyi * XS_ROW + xi * XS_LINE];
#pragma unroll
            for (int k = 0; k < 4; ++k)
                *(int4*)&dst[((chalf * 4 + k) ^ key) * 8] = *(int4*)&hb[k * 8];
        }
        // zero pad lines at x=-1 (line 0) and x=128 (line 129); all 8 chunks zeroed
        if (tid < 48) {
            int dyi = tid / 16;
            int rem = tid % 16;
            int xz  = (rem >= 8) ? 129 : 0;
            int k8  = rem & 7;
            int4 z  = {0, 0, 0, 0};
            *(int4*)&Xs[dyi * XS_ROW + xz * XS_LINE + k8 * 8] = z;
        }
    }

    // ---- A(0) preload: issue early so latency hides under the h-pack VALU ----
    const half8* wa8   = (const half8*)wa;           // frag index: (t*24 + j*4+mt)*64 + lane
    const half8* baseA = wa8 + lane;
    half8 A[6][4];
#pragma unroll
    for (int j = 0; j < 6; ++j)
#pragma unroll
        for (int mt = 0; mt < 4; ++mt)
            A[j][mt] = baseA[(j * 4 + mt) * 64];

    // ---- per-lane h-selection packs: 1 f64 divide per pixel (was 10) ----
    // u = (dw - d0)/s0 + 1.5 with s0 = d0/f  ==  (dw - d0)*(f/d0) + 1.5.
    // dd==0 -> inv=+-inf/nan -> conditions false -> h=-1 (matches old path).
    double fd = (double)(*fptr);
    unsigned hpk[2];
#pragma unroll
    for (int nt = 0; nt < 2; ++nt) {
        int x = p0 + nt * 16 + ln15;
        float d0f = depth[((size_t)b * H_N + y) * W_N + x];
        double dd  = (double)d0f;
        double inv = fd / dd;                        // sign(inv) == sign(s0)
        bool   pos = (inv > 0.0);
        unsigned pk = 0;
        for (int t = 0; t < 9; ++t) {
            int dy = t / 3 - 1, dx = t % 3 - 1;
            int yy = y + dy, xx = x + dx;
            float dwf = (yy >= 0 && yy < H_N && xx >= 0 && xx < W_N)
                        ? depth[((size_t)b * H_N + yy) * W_N + xx] : 0.f;
            int h = -1;
            if (pos) {
                double u  = ((double)dwf - dd) * inv + 1.5;
                double uf = floor(u);
                if (uf >= 0.0 && uf <= 2.0) h = (int)uf;
            }
            pk |= (unsigned)(h + 1) << (2 * t);
        }
        hpk[nt] = pk;
    }

    __syncthreads();

    // ---- MFMA main loop: fully unrolled 9 taps, A single-buffer prefetch,
    //      B double-buffered, both prefetched BEFORE the per-tap barrier ----
    f32x4 acc[4][2];
#pragma unroll
    for (int mt = 0; mt < 4; ++mt)
#pragma unroll
        for (int nt = 0; nt < 2; ++nt) acc[mt][nt] = (f32x4){0.f, 0.f, 0.f, 0.f};

    half8 bb[2][4];   // [t&1][ nt*2 + kk ]

#define READ_B(tt) {                                                          \
        int dyi_ = (tt) / 3; int dx_ = (tt) % 3 - 1;                          \
        int xs0_ = p0 + ln15 + dx_ + 1;                                       \
        int key_ = xs0_ & 7;                                                  \
        int ba0_ = dyi_ * XS_ROW + xs0_ * XS_LINE;                            \
        int ba1_ = ba0_ + 16 * XS_LINE;                                       \
        bb[(tt) & 1][0] = *(const half8*)&Xs[ba0_ + ((quad    ) ^ key_) * 8]; \
        bb[(tt) & 1][1] = *(const half8*)&Xs[ba0_ + ((quad + 4) ^ key_) * 8]; \
        bb[(tt) & 1][2] = *(const half8*)&Xs[ba1_ + ((quad    ) ^ key_) * 8]; \
        bb[(tt) & 1][3] = *(const half8*)&Xs[ba1_ + ((quad + 4) ^ key_) * 8]; \
    }

    READ_B(0);

    half8 z8 = {(_Float16)0.f, (_Float16)0.f, (_Float16)0.f, (_Float16)0.f,
                (_Float16)0.f, (_Float16)0.f, (_Float16)0.f, (_Float16)0.f};

#pragma unroll
    for (int t = 0; t < 9; ++t) {
        int hb0 = (hpk[0] >> (2 * t)) & 3;
        int hb1 = (hpk[1] >> (2 * t)) & 3;

        // accumulation order identical to R3/R4: (h, kk, mt, nt)
#pragma unroll
        for (int h = 0; h < 3; ++h) {
            bool m0 = (hb0 == h + 1);
            bool m1 = (hb1 == h + 1);
#pragma unroll
            for (int kk = 0; kk < 2; ++kk) {
                half8 c0 = m0 ? bb[t & 1][kk]     : z8;
                half8 c1 = m1 ? bb[t & 1][2 + kk] : z8;
                int j = h * 2 + kk;
#pragma unroll
                for (int mt = 0; mt < 4; ++mt) {
                    acc[mt][0] = __builtin_amdgcn_mfma_f32_16x16x32_f16(A[j][mt], c0, acc[mt][0], 0, 0, 0);
                    acc[mt][1] = __builtin_amdgcn_mfma_f32_16x16x32_f16(A[j][mt], c1, acc[mt][1], 0, 0, 0);
                }
            }
        }

        if (t < 8) {
            // prefetch next tap's A-frags (24 global loads, in flight across barrier)
            const half8* bA = baseA + (size_t)(t + 1) * 24 * 64;
#pragma unroll
            for (int j = 0; j < 6; ++j)
#pragma unroll
                for (int mt = 0; mt < 4; ++mt)
                    A[j][mt] = bA[(j * 4 + mt) * 64];
            READ_B(t + 1);
            __syncthreads();   // lockstep the block's waves -> shared L1 A-tile
        }
    }
#undef READ_B

    // ---- epilogue: D[m=o: quad*4+r][n=pixel: lane&15] + bias ----
#pragma unroll
    for (int mt = 0; mt < 4; ++mt) {
#pragma unroll
        for (int nt = 0; nt < 2; ++nt) {
            int x = p0 + nt * 16 + ln15;
#pragma unroll
            for (int r = 0; r < 4; ++r) {
                int o = mt * 16 + quad * 4 + r;
                out[(((size_t)b * COUT + o) * H_N + y) * W_N + x] = acc[mt][nt][r] + bias[o];
            }
        }
    }
}

// ---- fallback scalar kernel (used only if ws too small) ----
__global__ __launch_bounds__(256)
void conv25d(const float* __restrict__ inp, const float* __restrict__ depth,
             const float* __restrict__ wsrc, const float* __restrict__ bias,
             const int* __restrict__ fptr, float* __restrict__ out) {
    int bid = blockIdx.x;
    int xt  = bid & 3;
    int y   = (bid >> 2) & (H_N - 1);
    int b   = bid >> 9;
    int o   = threadIdx.x & 63;
    int q   = threadIdx.x >> 6;
    int x0  = xt * 32 + q * 8;
    double fd = (double)(*fptr);
    float acc[8];
    float bv = bias[o];
#pragma unroll
    for (int i = 0; i < 8; ++i) acc[i] = bv;
    const float* dcen = depth + ((size_t)b * H_N + y) * W_N;
    float d0[8];
#pragma unroll
    for (int i = 0; i < 8; ++i) d0[i] = dcen[x0 + i];
    for (int t = 0; t < 9; ++t) {
        int dy = t / 3 - 1, dx = t % 3 - 1;
        int yy = y + dy;
        if (yy < 0 || yy >= H_N) continue;
        const float* drow = depth + ((size_t)b * H_N + yy) * W_N;
        int hsel[8];
#pragma unroll
        for (int i = 0; i < 8; ++i) {
            int xx = x0 + i + dx;
            int h = -1;
            if (xx >= 0 && xx < W_N) {
                double dd = (double)d0[i];
                double s0 = dd / fd;
                if (s0 > 0.0) {
                    double u = ((double)drow[xx] - dd) / s0 + 1.5;
                    double uf = floor(u);
                    if (uf >= 0.0 && uf <= 2.0) h = (int)uf;
                }
            }
            hsel[i] = h;
        }
        const float* irow = inp + ((size_t)b * CIN * H_N + yy) * W_N;
        for (int c = 0; c < CIN; ++c) {
            const float* wb = wsrc + ((size_t)o * CIN + c) * 9 + t;
            float w0 = wb[0], w1 = wb[(size_t)COUT * CIN * 9], w2 = wb[2 * (size_t)COUT * CIN * 9];
            const float* ir = irow + (size_t)c * H_N * W_N;
#pragma unroll
            for (int i = 0; i < 8; ++i) {
                int h = hsel[i];
                if (h >= 0) {
                    float wv = (h == 0) ? w0 : ((h == 1) ? w1 : w2);
                    acc[i] = fmaf(ir[x0 + i + dx], wv, acc[i]);
                }
            }
        }
    }
    float* orow = out + (((size_t)b * COUT + o) * H_N + y) * W_N;
#pragma unroll
    for (int i = 0; i < 8; ++i) orow[x0 + i] = acc[i];
}

extern "C" void kernel_launch(void* const* d_in, const int* in_sizes, int n_in,
                              void* d_out, int out_size, void* d_ws, size_t ws_size,
                              hipStream_t stream) {
    const float* inp   = (const float*)d_in[0];
    const float* depth = (const float*)d_in[1];
    const float* w     = (const float*)d_in[2];
    const float* bias  = (const float*)d_in[3];
    const int*   f     = (const int*)d_in[4];
    float* out = (float*)d_out;

    if (ws_size >= WA_BYTES) {
        _Float16* wa = (_Float16*)d_ws;
        wprep<<<NSTEP, 256, 0, stream>>>(w, wa);
        conv_mfma<<<B_N * H_N, 256, 0, stream>>>(inp, depth, wa, bias, f, out);
    } else {
        conv25d<<<B_N * H_N * (W_N / 32), 256, 0, stream>>>(inp, depth, w, bias, f, out);
    }
}

// Round 3
// 101.158 us; speedup vs baseline: 1.0938x; 1.0269x over previous
//
#include <hip/hip_runtime.h>
#include <math.h>

#define B_N  4
#define CIN  64
#define COUT 64
#define H_N  128
#define W_N  128

typedef _Float16 half8 __attribute__((ext_vector_type(8)));
typedef float    f32x4 __attribute__((ext_vector_type(4)));

#define KTOT   1728              // 27 groups (t*3+h) * 64 c
#define NSTEP  54                // KTOT / 32
#define WA_BYTES ((size_t)NSTEP * 4 * 64 * 8 * 2)   // 221184 B

// ---- pack weights (3,Cout,Cin,3,3) fp32 -> f16 in MFMA A-fragment order ----
// A-fragment for K-step s, m-tile mt, lane l: 8 f16 = A[m=mt*16+(l&15)][k=s*32+(l>>4)*8+j]
// k -> (t,h,c): g=k>>6, c=k&63, t=g/3, h=g%3
__global__ void wprep(const float* __restrict__ w, _Float16* __restrict__ wa) {
    int idx = blockIdx.x * 256 + threadIdx.x;        // (s, mt, lane)
    if (idx >= NSTEP * 4 * 64) return;
    int lane = idx & 63;
    int mt   = (idx >> 6) & 3;
    int s    = idx >> 8;
    int m    = mt * 16 + (lane & 15);
    int kl0  = (lane >> 4) * 8;
    _Float16 v[8];
#pragma unroll
    for (int j = 0; j < 8; ++j) {
        int k = s * 32 + kl0 + j;
        int g = k >> 6;
        int c = k & 63;
        int t = g / 3;
        int h = g % 3;
        v[j] = (_Float16)w[(((size_t)(h * COUT) + m) * CIN + c) * 9 + t];
    }
    *(int4*)&wa[(size_t)idx * 8] = *(int4*)v;
}

// XOR chunk-swizzle LDS layout: line = 64 halfs (128 B) per (dy,x);
// logical 16-B chunk lc of line xi lives at halfs offset xi*64 + ((lc ^ (xi&7))*8).
#define XS_LINE 64
#define XS_ROW  (130 * XS_LINE)          // 8320 halfs per dy-plane

// R6: M-split across waves. Each wave: M=32 (2 m-tiles, mh=wid&1) x N=64
// (4 n-tiles, nq=wid>>1). Halves the per-CU A-fragment register-fill traffic
// (the R5 bottleneck: 8 waves x 24.5KB x 9 taps = 1.77 MB/CU through L1).
// MFMA count/wave unchanged; per-element accumulation order bitwise = R5.
__global__ __launch_bounds__(256, 2)
void conv_mfma(const float* __restrict__ inp, const float* __restrict__ depth,
               const _Float16* __restrict__ wa, const float* __restrict__ bias,
               const int* __restrict__ fptr, float* __restrict__ out) {
    __shared__ _Float16 Xs[3 * XS_ROW];              // 49920 B

    int bid  = blockIdx.x;
    int y    = bid & (H_N - 1);
    int b    = bid >> 7;
    int tid  = threadIdx.x;
    int lane = tid & 63;
    int wid  = tid >> 6;
    int mh   = wid & 1;                              // m-half: mt in {mh*2, mh*2+1}
    int nq   = wid >> 1;                             // n-quarter: pixels [nq*64, nq*64+64)
    int p0   = nq * 64;
    int ln15 = lane & 15;
    int quad = lane >> 4;

    // ---- stage 3 input rows (dy=-1,0,1), transposed to [x][c], f16, swizzled ----
    // All 96 global loads issued as one batch (max MLP), then convert+write.
    {
        int x     = tid & 127;
        int chalf = tid >> 7;                        // c in [chalf*32, chalf*32+32)
        int xi    = x + 1;
        int key   = xi & 7;
        float fbuf[3][32];
#pragma unroll
        for (int dyi = 0; dyi < 3; ++dyi) {
            int yy = y + dyi - 1;
            if (yy >= 0 && yy < H_N) {
                const float* src = inp + (((size_t)b * CIN + chalf * 32) * H_N + yy) * W_N + x;
#pragma unroll
                for (int cc = 0; cc < 32; ++cc)
                    fbuf[dyi][cc] = src[(size_t)cc * H_N * W_N];
            } else {
#pragma unroll
                for (int cc = 0; cc < 32; ++cc) fbuf[dyi][cc] = 0.f;
            }
        }
#pragma unroll
        for (int dyi = 0; dyi < 3; ++dyi) {
            _Float16 hb[32];
#pragma unroll
            for (int cc = 0; cc < 32; ++cc) hb[cc] = (_Float16)fbuf[dyi][cc];
            _Float16* dst = &Xs[dyi * XS_ROW + xi * XS_LINE];
#pragma unroll
            for (int k = 0; k < 4; ++k)
                *(int4*)&dst[((chalf * 4 + k) ^ key) * 8] = *(int4*)&hb[k * 8];
        }
        // zero pad lines at x=-1 (line 0) and x=128 (line 129); all 8 chunks zeroed
        if (tid < 48) {
            int dyi = tid / 16;
            int rem = tid % 16;
            int xz  = (rem >= 8) ? 129 : 0;
            int k8  = rem & 7;
            int4 z  = {0, 0, 0, 0};
            *(int4*)&Xs[dyi * XS_ROW + xz * XS_LINE + k8 * 8] = z;
        }
    }

    // ---- A(0) preload: 12 frags (6 K-steps x 2 m-tiles of this wave's m-half) ----
    const half8* wa8 = (const half8*)wa;   // frag index: (t*24 + j*4 + mt)*64 + lane
    half8 A[6][2];
    {
        const half8* bA = wa8 + ((size_t)0 * 24 + mh * 2) * 64 + lane;
#pragma unroll
        for (int j = 0; j < 6; ++j)
#pragma unroll
            for (int mtl = 0; mtl < 2; ++mtl)
                A[j][mtl] = bA[(j * 4 + mtl) * 64];
    }

    // ---- per-lane h-selection packs: 1 f64 divide per pixel (4 pixels/lane) ----
    // u = (dw - d0)*(f/d0) + 1.5; dd==0 -> inv=inf/nan -> h=-1 (matches exact path)
    double fd = (double)(*fptr);
    unsigned hpk[4];
#pragma unroll
    for (int nt = 0; nt < 4; ++nt) {
        int x = p0 + nt * 16 + ln15;
        float d0f = depth[((size_t)b * H_N + y) * W_N + x];
        double dd  = (double)d0f;
        double inv = fd / dd;
        bool   pos = (inv > 0.0);
        unsigned pk = 0;
        for (int t = 0; t < 9; ++t) {
            int dy = t / 3 - 1, dx = t % 3 - 1;
            int yy = y + dy, xx = x + dx;
            float dwf = (yy >= 0 && yy < H_N && xx >= 0 && xx < W_N)
                        ? depth[((size_t)b * H_N + yy) * W_N + xx] : 0.f;
            int h = -1;
            if (pos) {
                double u  = ((double)dwf - dd) * inv + 1.5;
                double uf = floor(u);
                if (uf >= 0.0 && uf <= 2.0) h = (int)uf;
            }
            pk |= (unsigned)(h + 1) << (2 * t);
        }
        hpk[nt] = pk;
    }

    __syncthreads();

    // ---- MFMA main loop: fully unrolled 9 taps; A single-buffer prefetch,
    //      B double-buffered, both issued BEFORE the per-tap barrier ----
    f32x4 acc[2][4];                                 // [mtl][nt]
#pragma unroll
    for (int mtl = 0; mtl < 2; ++mtl)
#pragma unroll
        for (int nt = 0; nt < 4; ++nt) acc[mtl][nt] = (f32x4){0.f, 0.f, 0.f, 0.f};

    half8 bb[2][8];   // [t&1][nt*2 + kk]

#define READ_B(tt) {                                                              \
        int dyi_ = (tt) / 3; int dx_ = (tt) % 3 - 1;                              \
        _Pragma("unroll")                                                         \
        for (int nt_ = 0; nt_ < 4; ++nt_) {                                       \
            int xs_  = p0 + nt_ * 16 + ln15 + dx_ + 1;                            \
            int key_ = xs_ & 7;                                                   \
            int ba_  = dyi_ * XS_ROW + xs_ * XS_LINE;                             \
            bb[(tt) & 1][nt_ * 2 + 0] = *(const half8*)&Xs[ba_ + ((quad    ) ^ key_) * 8]; \
            bb[(tt) & 1][nt_ * 2 + 1] = *(const half8*)&Xs[ba_ + ((quad + 4) ^ key_) * 8]; \
        }                                                                         \
    }

    READ_B(0);

    half8 z8 = {(_Float16)0.f, (_Float16)0.f, (_Float16)0.f, (_Float16)0.f,
                (_Float16)0.f, (_Float16)0.f, (_Float16)0.f, (_Float16)0.f};

#pragma unroll
    for (int t = 0; t < 9; ++t) {
        int hb[4];
#pragma unroll
        for (int nt = 0; nt < 4; ++nt) hb[nt] = (hpk[nt] >> (2 * t)) & 3;

        // accumulation order per output element identical to R5: (h, kk) asc
#pragma unroll
        for (int h = 0; h < 3; ++h) {
#pragma unroll
            for (int kk = 0; kk < 2; ++kk) {
                int j = h * 2 + kk;
#pragma unroll
                for (int nt = 0; nt < 4; ++nt) {
                    half8 c = (hb[nt] == h + 1) ? bb[t & 1][nt * 2 + kk] : z8;
                    acc[0][nt] = __builtin_amdgcn_mfma_f32_16x16x32_f16(A[j][0], c, acc[0][nt], 0, 0, 0);
                    acc[1][nt] = __builtin_amdgcn_mfma_f32_16x16x32_f16(A[j][1], c, acc[1][nt], 0, 0, 0);
                }
            }
        }

        if (t < 8) {
            // prefetch next tap's A-frags (12 loads, in flight across the barrier)
            const half8* bA = wa8 + ((size_t)(t + 1) * 24 + mh * 2) * 64 + lane;
#pragma unroll
            for (int j = 0; j < 6; ++j)
#pragma unroll
                for (int mtl = 0; mtl < 2; ++mtl)
                    A[j][mtl] = bA[(j * 4 + mtl) * 64];
            READ_B(t + 1);
            __syncthreads();   // lockstep the block's waves -> shared L1 A-tile
        }
    }
#undef READ_B

    // ---- epilogue: D[m=o: quad*4+r][n=pixel: lane&15] + bias ----
#pragma unroll
    for (int mtl = 0; mtl < 2; ++mtl) {
#pragma unroll
        for (int nt = 0; nt < 4; ++nt) {
            int x = p0 + nt * 16 + ln15;
#pragma unroll
            for (int r = 0; r < 4; ++r) {
                int o = (mh * 2 + mtl) * 16 + quad * 4 + r;
                out[(((size_t)b * COUT + o) * H_N + y) * W_N + x] = acc[mtl][nt][r] + bias[o];
            }
        }
    }
}

// ---- fallback scalar kernel (used only if ws too small) ----
__global__ __launch_bounds__(256)
void conv25d(const float* __restrict__ inp, const float* __restrict__ depth,
             const float* __restrict__ wsrc, const float* __restrict__ bias,
             const int* __restrict__ fptr, float* __restrict__ out) {
    int bid = blockIdx.x;
    int xt  = bid & 3;
    int y   = (bid >> 2) & (H_N - 1);
    int b   = bid >> 9;
    int o   = threadIdx.x & 63;
    int q   = threadIdx.x >> 6;
    int x0  = xt * 32 + q * 8;
    double fd = (double)(*fptr);
    float acc[8];
    float bv = bias[o];
#pragma unroll
    for (int i = 0; i < 8; ++i) acc[i] = bv;
    const float* dcen = depth + ((size_t)b * H_N + y) * W_N;
    float d0[8];
#pragma unroll
    for (int i = 0; i < 8; ++i) d0[i] = dcen[x0 + i];
    for (int t = 0; t < 9; ++t) {
        int dy = t / 3 - 1, dx = t % 3 - 1;
        int yy = y + dy;
        if (yy < 0 || yy >= H_N) continue;
        const float* drow = depth + ((size_t)b * H_N + yy) * W_N;
        int hsel[8];
#pragma unroll
        for (int i = 0; i < 8; ++i) {
            int xx = x0 + i + dx;
            int h = -1;
            if (xx >= 0 && xx < W_N) {
                double dd = (double)d0[i];
                double s0 = dd / fd;
                if (s0 > 0.0) {
                    double u = ((double)drow[xx] - dd) / s0 + 1.5;
                    double uf = floor(u);
                    if (uf >= 0.0 && uf <= 2.0) h = (int)uf;
                }
            }
            hsel[i] = h;
        }
        const float* irow = inp + ((size_t)b * CIN * H_N + yy) * W_N;
        for (int c = 0; c < CIN; ++c) {
            const float* wb = wsrc + ((size_t)o * CIN + c) * 9 + t;
            float w0 = wb[0], w1 = wb[(size_t)COUT * CIN * 9], w2 = wb[2 * (size_t)COUT * CIN * 9];
            const float* ir = irow + (size_t)c * H_N * W_N;
#pragma unroll
            for (int i = 0; i < 8; ++i) {
                int h = hsel[i];
                if (h >= 0) {
                    float wv = (h == 0) ? w0 : ((h == 1) ? w1 : w2);
                    acc[i] = fmaf(ir[x0 + i + dx], wv, acc[i]);
                }
            }
        }
    }
    float* orow = out + (((size_t)b * COUT + o) * H_N + y) * W_N;
#pragma unroll
    for (int i = 0; i < 8; ++i) orow[x0 + i] = acc[i];
}

extern "C" void kernel_launch(void* const* d_in, const int* in_sizes, int n_in,
                              void* d_out, int out_size, void* d_ws, size_t ws_size,
                              hipStream_t stream) {
    const float* inp   = (const float*)d_in[0];
    const float* depth = (const float*)d_in[1];
    const float* w     = (const float*)d_in[2];
    const float* bias  = (const float*)d_in[3];
    const int*   f     = (const int*)d_in[4];
    float* out = (float*)d_out;

    if (ws_size >= WA_BYTES) {
        _Float16* wa = (_Float16*)d_ws;
        wprep<<<NSTEP, 256, 0, stream>>>(w, wa);
        conv_mfma<<<B_N * H_N, 256, 0, stream>>>(inp, depth, wa, bias, f, out);
    } else {
        conv25d<<<B_N * H_N * (W_N / 32), 256, 0, stream>>>(inp, depth, w, bias, f, out);
    }
}

// Round 4
// 100.154 us; speedup vs baseline: 1.1048x; 1.0100x over previous
//
#include <hip/hip_runtime.h>
#include <math.h>

#define B_N  4
#define CIN  64
#define COUT 64
#define H_N  128
#define W_N  128

typedef _Float16 half8 __attribute__((ext_vector_type(8)));
typedef float    f32x4 __attribute__((ext_vector_type(4)));

#define KTOT   1728              // 27 groups (t*3+h) * 64 c
#define NSTEP  54                // KTOT / 32
#define WA_BYTES ((size_t)NSTEP * 4 * 64 * 8 * 2)   // 221184 B

// ---- pack weights (3,Cout,Cin,3,3) fp32 -> f16 in MFMA A-fragment order ----
// A-fragment for K-step s, m-tile mt, lane l: 8 f16 = A[m=mt*16+(l&15)][k=s*32+(l>>4)*8+j]
// k -> (t,h,c): g=k>>6, c=k&63, t=g/3, h=g%3
__global__ void wprep(const float* __restrict__ w, _Float16* __restrict__ wa) {
    int idx = blockIdx.x * 256 + threadIdx.x;        // (s, mt, lane)
    if (idx >= NSTEP * 4 * 64) return;
    int lane = idx & 63;
    int mt   = (idx >> 6) & 3;
    int s    = idx >> 8;
    int m    = mt * 16 + (lane & 15);
    int kl0  = (lane >> 4) * 8;
    _Float16 v[8];
#pragma unroll
    for (int j = 0; j < 8; ++j) {
        int k = s * 32 + kl0 + j;
        int g = k >> 6;
        int c = k & 63;
        int t = g / 3;
        int h = g % 3;
        v[j] = (_Float16)w[(((size_t)(h * COUT) + m) * CIN + c) * 9 + t];
    }
    *(int4*)&wa[(size_t)idx * 8] = *(int4*)v;
}

// XOR chunk-swizzle LDS layout: line = 64 halfs (128 B) per (dy, local x);
// logical 16-B chunk lc of line xi lives at halfs offset xi*64 + ((lc ^ (xi&7))*8).
#define XS_LINE 64
#define XS_ROW  (66 * XS_LINE)           // 4224 halfs per dy-plane (66 lines: halo+64+halo)

// R7: x-split + M-split + barrier-free main loop.
// Grid 1024 = (b, y, xh); block = 64 px x 64 Cout, 4 waves; wave wid owns
// m-tile mq=wid (16 Cout rows) x all 64 px. LDS 25.6 KB -> 4 blocks/CU
// (exactly one dispatch round), 4 waves/SIMD. No main-loop barriers (Xs is
// read-only after staging); A double-buffered in registers across taps.
__global__ __launch_bounds__(256, 4)
void conv_mfma(const float* __restrict__ inp, const float* __restrict__ depth,
               const _Float16* __restrict__ wa, const float* __restrict__ bias,
               const int* __restrict__ fptr, float* __restrict__ out) {
    __shared__ _Float16 Xs[3 * XS_ROW];              // 25344 B
    __shared__ unsigned hLds[64];                    // per-pixel h-selection packs

    int bid  = blockIdx.x;
    int xh   = bid & 1;
    int y    = (bid >> 1) & (H_N - 1);
    int b    = bid >> 8;
    int x0   = xh * 64;
    int tid  = threadIdx.x;
    int lane = tid & 63;
    int mq   = tid >> 6;                             // wave id = m-quarter
    int ln15 = lane & 15;
    int quad = lane >> 4;

    // ---- stage 3 input rows (dy=-1,0,1), local x in [-1,64], [x][c] f16 swizzled ----
    {
        int xl  = tid & 63;                          // local interior x
        int cq  = tid >> 6;                          // c-quarter: c in [cq*16, cq*16+16)
        int xi  = xl + 1;
        int key = xi & 7;
#pragma unroll
        for (int dyi = 0; dyi < 3; ++dyi) {
            int yy = y + dyi - 1;
            _Float16 hb[16];
            if (yy >= 0 && yy < H_N) {
                const float* src = inp + (((size_t)b * CIN + cq * 16) * H_N + yy) * W_N + (x0 + xl);
                float tf[16];
#pragma unroll
                for (int cc = 0; cc < 16; ++cc) tf[cc] = src[(size_t)cc * H_N * W_N];
#pragma unroll
                for (int cc = 0; cc < 16; ++cc) hb[cc] = (_Float16)tf[cc];
            } else {
#pragma unroll
                for (int cc = 0; cc < 16; ++cc) hb[cc] = (_Float16)0.f;
            }
            _Float16* dst = &Xs[dyi * XS_ROW + xi * XS_LINE];
            *(int4*)&dst[((cq * 2    ) ^ key) * 8] = *(int4*)&hb[0];
            *(int4*)&dst[((cq * 2 + 1) ^ key) * 8] = *(int4*)&hb[8];
        }
        // halo lines xi=0 (x=x0-1) and xi=65 (x=x0+64): real pixels or zeros
        if (tid < 48) {
            int dyi  = tid >> 4;                     // 0..2
            int rem  = tid & 15;
            int side = rem >> 3;                     // 0 -> xi=0, 1 -> xi=65
            int ck   = rem & 7;                      // 8-half chunk: c = ck*8..
            int xi2  = side ? 65 : 0;
            int xg   = x0 + xi2 - 1;
            int key2 = xi2 & 7;
            int yy   = y + dyi - 1;
            _Float16 hb[8];
            if (xg >= 0 && xg < W_N && yy >= 0 && yy < H_N) {
                const float* src = inp + (((size_t)b * CIN + ck * 8) * H_N + yy) * W_N + xg;
#pragma unroll
                for (int cc = 0; cc < 8; ++cc) hb[cc] = (_Float16)src[(size_t)cc * H_N * W_N];
            } else {
#pragma unroll
                for (int cc = 0; cc < 8; ++cc) hb[cc] = (_Float16)0.f;
            }
            *(int4*)&Xs[dyi * XS_ROW + xi2 * XS_LINE + (ck ^ key2) * 8] = *(int4*)&hb[0];
        }
    }

    // ---- A(0) preload (6 frags for this wave's m-quarter); issue early ----
    const half8* wa8 = (const half8*)wa;   // frag index: (t*24 + j*4 + mt)*64 + lane
    half8 Abuf[2][6];
    {
        const half8* bA = wa8 + (size_t)mq * 64 + lane;
#pragma unroll
        for (int j = 0; j < 6; ++j) Abuf[0][j] = bA[(size_t)j * 4 * 64];
    }

    // ---- h-selection packs: one pixel per thread (wave 0 only), LDS broadcast ----
    // u = (dw - d0)*(f/d0) + 1.5; dd==0 -> inv=inf/nan -> h=-1 (matches exact path)
    if (tid < 64) {
        int x = x0 + tid;
        double fd  = (double)(*fptr);
        float  d0f = depth[((size_t)b * H_N + y) * W_N + x];
        double dd  = (double)d0f;
        double inv = fd / dd;
        bool   pos = (inv > 0.0);
        unsigned pk = 0;
        for (int t = 0; t < 9; ++t) {
            int dy = t / 3 - 1, dx = t % 3 - 1;
            int yy = y + dy, xx = x + dx;
            float dwf = (yy >= 0 && yy < H_N && xx >= 0 && xx < W_N)
                        ? depth[((size_t)b * H_N + yy) * W_N + xx] : 0.f;
            int h = -1;
            if (pos) {
                double u  = ((double)dwf - dd) * inv + 1.5;
                double uf = floor(u);
                if (uf >= 0.0 && uf <= 2.0) h = (int)uf;
            }
            pk |= (unsigned)(h + 1) << (2 * t);
        }
        hLds[tid] = pk;
    }

    __syncthreads();                                 // the ONLY barrier

    unsigned hpk[4];
#pragma unroll
    for (int nt = 0; nt < 4; ++nt) hpk[nt] = hLds[nt * 16 + ln15];

    // ---- MFMA main loop: 9 taps fully unrolled, no barriers.
    //      B single-buffered (8 ds_reads/tap), A double-buffered (6 loads/tap,
    //      one-tap prefetch distance -> vmcnt-pipelined). ----
    f32x4 acc[4];                                    // [nt]
#pragma unroll
    for (int nt = 0; nt < 4; ++nt) acc[nt] = (f32x4){0.f, 0.f, 0.f, 0.f};

    half8 z8 = {(_Float16)0.f, (_Float16)0.f, (_Float16)0.f, (_Float16)0.f,
                (_Float16)0.f, (_Float16)0.f, (_Float16)0.f, (_Float16)0.f};

#pragma unroll
    for (int t = 0; t < 9; ++t) {
        int dyi = t / 3;
        int dx  = t % 3 - 1;

        // B(t): 8 ds_read_b128
        half8 bb[8];
#pragma unroll
        for (int nt = 0; nt < 4; ++nt) {
            int xs = nt * 16 + ln15 + dx + 1;        // in [0, 65]
            int k2 = xs & 7;
            int ba = dyi * XS_ROW + xs * XS_LINE;
            bb[nt * 2 + 0] = *(const half8*)&Xs[ba + ((quad    ) ^ k2) * 8];
            bb[nt * 2 + 1] = *(const half8*)&Xs[ba + ((quad + 4) ^ k2) * 8];
        }

        // A(t+1) prefetch into the other register buffer
        if (t < 8) {
            const half8* bA = wa8 + ((size_t)(t + 1) * 24 + mq) * 64 + lane;
#pragma unroll
            for (int j = 0; j < 6; ++j) Abuf[(t + 1) & 1][j] = bA[(size_t)j * 4 * 64];
        }

        int hb[4];
#pragma unroll
        for (int nt = 0; nt < 4; ++nt) hb[nt] = (hpk[nt] >> (2 * t)) & 3;

        // accumulation order per output element identical to R5/R6: (h, kk) asc
#pragma unroll
        for (int h = 0; h < 3; ++h) {
#pragma unroll
            for (int kk = 0; kk < 2; ++kk) {
                int j = h * 2 + kk;
#pragma unroll
                for (int nt = 0; nt < 4; ++nt) {
                    half8 c = (hb[nt] == h + 1) ? bb[nt * 2 + kk] : z8;
                    acc[nt] = __builtin_amdgcn_mfma_f32_16x16x32_f16(Abuf[t & 1][j], c, acc[nt], 0, 0, 0);
                }
            }
        }
    }

    // ---- epilogue: D[m=o: quad*4+r][n=pixel: lane&15] + bias ----
#pragma unroll
    for (int nt = 0; nt < 4; ++nt) {
        int x = x0 + nt * 16 + ln15;
#pragma unroll
        for (int r = 0; r < 4; ++r) {
            int o = mq * 16 + quad * 4 + r;
            out[(((size_t)b * COUT + o) * H_N + y) * W_N + x] = acc[nt][r] + bias[o];
        }
    }
}

// ---- fallback scalar kernel (used only if ws too small) ----
__global__ __launch_bounds__(256)
void conv25d(const float* __restrict__ inp, const float* __restrict__ depth,
             const float* __restrict__ wsrc, const float* __restrict__ bias,
             const int* __restrict__ fptr, float* __restrict__ out) {
    int bid = blockIdx.x;
    int xt  = bid & 3;
    int y   = (bid >> 2) & (H_N - 1);
    int b   = bid >> 9;
    int o   = threadIdx.x & 63;
    int q   = threadIdx.x >> 6;
    int x0  = xt * 32 + q * 8;
    double fd = (double)(*fptr);
    float acc[8];
    float bv = bias[o];
#pragma unroll
    for (int i = 0; i < 8; ++i) acc[i] = bv;
    const float* dcen = depth + ((size_t)b * H_N + y) * W_N;
    float d0[8];
#pragma unroll
    for (int i = 0; i < 8; ++i) d0[i] = dcen[x0 + i];
    for (int t = 0; t < 9; ++t) {
        int dy = t / 3 - 1, dx = t % 3 - 1;
        int yy = y + dy;
        if (yy < 0 || yy >= H_N) continue;
        const float* drow = depth + ((size_t)b * H_N + yy) * W_N;
        int hsel[8];
#pragma unroll
        for (int i = 0; i < 8; ++i) {
            int xx = x0 + i + dx;
            int h = -1;
            if (xx >= 0 && xx < W_N) {
                double dd = (double)d0[i];
                double s0 = dd / fd;
                if (s0 > 0.0) {
                    double u = ((double)drow[xx] - dd) / s0 + 1.5;
                    double uf = floor(u);
                    if (uf >= 0.0 && uf <= 2.0) h = (int)uf;
                }
            }
            hsel[i] = h;
        }
        const float* irow = inp + ((size_t)b * CIN * H_N + yy) * W_N;
        for (int c = 0; c < CIN; ++c) {
            const float* wb = wsrc + ((size_t)o * CIN + c) * 9 + t;
            float w0 = wb[0], w1 = wb[(size_t)COUT * CIN * 9], w2 = wb[2 * (size_t)COUT * CIN * 9];
            const float* ir = irow + (size_t)c * H_N * W_N;
#pragma unroll
            for (int i = 0; i < 8; ++i) {
                int h = hsel[i];
                if (h >= 0) {
                    float wv = (h == 0) ? w0 : ((h == 1) ? w1 : w2);
                    acc[i] = fmaf(ir[x0 + i + dx], wv, acc[i]);
                }
            }
        }
    }
    float* orow = out + (((size_t)b * COUT + o) * H_N + y) * W_N;
#pragma unroll
    for (int i = 0; i < 8; ++i) orow[x0 + i] = acc[i];
}

extern "C" void kernel_launch(void* const* d_in, const int* in_sizes, int n_in,
                              void* d_out, int out_size, void* d_ws, size_t ws_size,
                              hipStream_t stream) {
    const float* inp   = (const float*)d_in[0];
    const float* depth = (const float*)d_in[1];
    const float* w     = (const float*)d_in[2];
    const float* bias  = (const float*)d_in[3];
    const int*   f     = (const int*)d_in[4];
    float* out = (float*)d_out;

    if (ws_size >= WA_BYTES) {
        _Float16* wa = (_Float16*)d_ws;
        wprep<<<NSTEP, 256, 0, stream>>>(w, wa);
        conv_mfma<<<B_N * H_N * 2, 256, 0, stream>>>(inp, depth, wa, bias, f, out);
    } else {
        conv25d<<<B_N * H_N * (W_N / 32), 256, 0, stream>>>(inp, depth, w, bias, f, out);
    }
}

// Round 7
// 99.503 us; speedup vs baseline: 1.1120x; 1.0065x over previous
//
#include <hip/hip_runtime.h>
#include <math.h>

#define B_N  4
#define CIN  64
#define COUT 64
#define H_N  128
#define W_N  128

typedef _Float16 half8 __attribute__((ext_vector_type(8)));
typedef float    f32x4 __attribute__((ext_vector_type(4)));

#define KTOT   1728              // 27 groups (t*3+h) * 64 c
#define NSTEP  54                // KTOT / 32
#define WA_BYTES ((size_t)NSTEP * 4 * 64 * 8 * 2)   // 221184 B

// ---- pack weights (3,Cout,Cin,3,3) fp32 -> f16 in MFMA A-fragment order ----
// A-fragment for K-step s, m-tile mt, lane l: 8 f16 = A[m=mt*16+(l&15)][k=s*32+(l>>4)*8+j]
// k -> (t,h,c): g=k>>6, c=k&63, t=g/3, h=g%3
__global__ void wprep(const float* __restrict__ w, _Float16* __restrict__ wa) {
    int idx = blockIdx.x * 256 + threadIdx.x;        // (s, mt, lane)
    if (idx >= NSTEP * 4 * 64) return;
    int lane = idx & 63;
    int mt   = (idx >> 6) & 3;
    int s    = idx >> 8;
    int m    = mt * 16 + (lane & 15);
    int kl0  = (lane >> 4) * 8;
    _Float16 v[8];
#pragma unroll
    for (int j = 0; j < 8; ++j) {
        int k = s * 32 + kl0 + j;
        int g = k >> 6;
        int c = k & 63;
        int t = g / 3;
        int h = g % 3;
        v[j] = (_Float16)w[(((size_t)(h * COUT) + m) * CIN + c) * 9 + t];
    }
    *(int4*)&wa[(size_t)idx * 8] = *(int4*)v;
}

// XOR chunk-swizzle LDS layout: line = 64 halfs (128 B) per (dy, local x);
// logical 16-B chunk lc of line xi lives at halfs offset xi*64 + ((lc ^ (xi&7))*8).
#define XS_LINE 64
#define XS_ROW  (66 * XS_LINE)           // 4224 halfs per dy-plane (66 lines: halo+64+halo)

// R8: row-pipelined staging. Taps group by dy-row (t=0-2 -> row y-1, 3-5 -> y,
// 6-8 -> y+1), so stage row r+1 DURING the taps of row r: global loads issued
// before the tap MFMAs, convert+ds_write after, one barrier per phase (2 total
// in main loop). launch_bounds (256,3): <=168 VGPR (no spill risk) and 3
// blocks/CU -> staggered rounds overlap late staging with early epilogues.
__global__ __launch_bounds__(256, 3)
void conv_mfma(const float* __restrict__ inp, const float* __restrict__ depth,
               const _Float16* __restrict__ wa, const float* __restrict__ bias,
               const int* __restrict__ fptr, float* __restrict__ out) {
    __shared__ _Float16 Xs[3 * XS_ROW];              // 25344 B
    __shared__ unsigned hLds[64];                    // per-pixel h-selection packs

    int bid  = blockIdx.x;
    int xh   = bid & 1;
    int y    = (bid >> 1) & (H_N - 1);
    int b    = bid >> 8;
    int x0   = xh * 64;
    int tid  = threadIdx.x;
    int lane = tid & 63;
    int mq   = tid >> 6;                             // wave id = m-quarter
    int ln15 = lane & 15;
    int quad = lane >> 4;

    // staging thread roles (fixed for all rows)
    int xl   = tid & 63;                             // interior local x
    int cq   = tid >> 6;                             // c-quarter: c in [cq*16, cq*16+16)
    int xi   = xl + 1;
    int key  = xi & 7;
    int side = (tid >> 3) & 1;                       // halo role for tid<16
    int ck   = tid & 7;
    int xi2  = side ? 65 : 0;
    int xg   = x0 + xi2 - 1;
    int key2 = xi2 & 7;

    const size_t HW = (size_t)H_N * W_N;

#define LOAD_ROW(dyi, buf, hbuf) {                                            \
        int yy_ = y + (dyi) - 1;                                              \
        if (yy_ >= 0 && yy_ < H_N) {                                          \
            const float* src_ = inp + (((size_t)b * CIN + cq * 16) * H_N + yy_) * W_N + (x0 + xl); \
            _Pragma("unroll")                                                 \
            for (int cc = 0; cc < 16; ++cc) buf[cc] = src_[(size_t)cc * HW];  \
        } else {                                                              \
            _Pragma("unroll")                                                 \
            for (int cc = 0; cc < 16; ++cc) buf[cc] = 0.f;                    \
        }                                                                     \
        if (tid < 16) {                                                       \
            if (xg >= 0 && xg < W_N && yy_ >= 0 && yy_ < H_N) {               \
                const float* hsrc_ = inp + (((size_t)b * CIN + ck * 8) * H_N + yy_) * W_N + xg; \
                _Pragma("unroll")                                             \
                for (int cc = 0; cc < 8; ++cc) hbuf[cc] = hsrc_[(size_t)cc * HW]; \
            } else {                                                          \
                _Pragma("unroll")                                             \
                for (int cc = 0; cc < 8; ++cc) hbuf[cc] = 0.f;                \
            }                                                                 \
        }                                                                     \
    }

#define WRITE_ROW(dyi, buf, hbuf) {                                           \
        _Float16 hb_[16];                                                     \
        _Pragma("unroll")                                                     \
        for (int cc = 0; cc < 16; ++cc) hb_[cc] = (_Float16)buf[cc];          \
        _Float16* dst_ = &Xs[(dyi) * XS_ROW + xi * XS_LINE];                  \
        *(int4*)&dst_[((cq * 2    ) ^ key) * 8] = *(int4*)&hb_[0];            \
        *(int4*)&dst_[((cq * 2 + 1) ^ key) * 8] = *(int4*)&hb_[8];            \
        if (tid < 16) {                                                       \
            _Float16 hh_[8];                                                  \
            _Pragma("unroll")                                                 \
            for (int cc = 0; cc < 8; ++cc) hh_[cc] = (_Float16)hbuf[cc];      \
            *(int4*)&Xs[(dyi) * XS_ROW + xi2 * XS_LINE + (ck ^ key2) * 8] = *(int4*)&hh_[0]; \
        }                                                                     \
    }

    // ---- prologue: stage row 0; A(0) preload; h-pack (wave 0) ----
    const half8* wa8 = (const half8*)wa;   // frag index: (t*24 + j*4 + mt)*64 + lane
    half8 Abuf[2][6];

    float rbuf[16];
    float rhbuf[8];
    LOAD_ROW(0, rbuf, rhbuf);

    {
        const half8* bA = wa8 + (size_t)mq * 64 + lane;
#pragma unroll
        for (int j = 0; j < 6; ++j) Abuf[0][j] = bA[(size_t)j * 4 * 64];
    }

    // h-selection packs: one pixel per thread (wave 0 only), LDS broadcast
    // u = (dw - d0)*(f/d0) + 1.5; dd==0 -> inv=inf/nan -> h=-1 (matches exact path)
    if (tid < 64) {
        int x = x0 + tid;
        double fd  = (double)(*fptr);
        float  d0f = depth[((size_t)b * H_N + y) * W_N + x];
        double dd  = (double)d0f;
        double inv = fd / dd;
        bool   pos = (inv > 0.0);
        unsigned pk = 0;
        for (int t = 0; t < 9; ++t) {
            int dy = t / 3 - 1, dx = t % 3 - 1;
            int yy = y + dy, xx = x + dx;
            float dwf = (yy >= 0 && yy < H_N && xx >= 0 && xx < W_N)
                        ? depth[((size_t)b * H_N + yy) * W_N + xx] : 0.f;
            int h = -1;
            if (pos) {
                double u  = ((double)dwf - dd) * inv + 1.5;
                double uf = floor(u);
                if (uf >= 0.0 && uf <= 2.0) h = (int)uf;
            }
            pk |= (unsigned)(h + 1) << (2 * t);
        }
        hLds[tid] = pk;
    }

    WRITE_ROW(0, rbuf, rhbuf);
    __syncthreads();

    unsigned hpk[4];
#pragma unroll
    for (int nt = 0; nt < 4; ++nt) hpk[nt] = hLds[nt * 16 + ln15];

    // ---- main loop: 3 phases (one dy-row each), 3 taps per phase ----
    f32x4 acc[4];                                    // [nt]
#pragma unroll
    for (int nt = 0; nt < 4; ++nt) acc[nt] = (f32x4){0.f, 0.f, 0.f, 0.f};

    half8 z8 = {(_Float16)0.f, (_Float16)0.f, (_Float16)0.f, (_Float16)0.f,
                (_Float16)0.f, (_Float16)0.f, (_Float16)0.f, (_Float16)0.f};

#pragma unroll
    for (int r = 0; r < 3; ++r) {
        // issue next row's global loads (land during this phase's MFMAs)
        float nbuf[16];
        float nhbuf[8];
        if (r < 2) LOAD_ROW(r + 1, nbuf, nhbuf);

#pragma unroll
        for (int dxl = 0; dxl < 3; ++dxl) {
            int t  = r * 3 + dxl;
            int dx = dxl - 1;

            // B(t): 8 ds_read_b128 from row r's plane
            half8 bb[8];
#pragma unroll
            for (int nt = 0; nt < 4; ++nt) {
                int xs = nt * 16 + ln15 + dx + 1;    // in [0, 65]
                int k2 = xs & 7;
                int ba = r * XS_ROW + xs * XS_LINE;
                bb[nt * 2 + 0] = *(const half8*)&Xs[ba + ((quad    ) ^ k2) * 8];
                bb[nt * 2 + 1] = *(const half8*)&Xs[ba + ((quad + 4) ^ k2) * 8];
            }

            // A(t+1) prefetch into the other register buffer
            if (t < 8) {
                const half8* bA = wa8 + ((size_t)(t + 1) * 24 + mq) * 64 + lane;
#pragma unroll
                for (int j = 0; j < 6; ++j) Abuf[(t + 1) & 1][j] = bA[(size_t)j * 4 * 64];
            }

            int hb[4];
#pragma unroll
            for (int nt = 0; nt < 4; ++nt) hb[nt] = (hpk[nt] >> (2 * t)) & 3;

            // accumulation order per output element identical to R5-R7: (h, kk) asc
#pragma unroll
            for (int h = 0; h < 3; ++h) {
#pragma unroll
                for (int kk = 0; kk < 2; ++kk) {
                    int j = h * 2 + kk;
#pragma unroll
                    for (int nt = 0; nt < 4; ++nt) {
                        half8 c = (hb[nt] == h + 1) ? bb[nt * 2 + kk] : z8;
                        acc[nt] = __builtin_amdgcn_mfma_f32_16x16x32_f16(Abuf[t & 1][j], c, acc[nt], 0, 0, 0);
                    }
                }
            }
        }

        if (r < 2) {
            WRITE_ROW(r + 1, nbuf, nhbuf);
            __syncthreads();                         // row r+1 visible before its taps
        }
    }
#undef LOAD_ROW
#undef WRITE_ROW

    // ---- epilogue: D[m=o: quad*4+r][n=pixel: lane&15] + bias ----
#pragma unroll
    for (int nt = 0; nt < 4; ++nt) {
        int x = x0 + nt * 16 + ln15;
#pragma unroll
        for (int rr = 0; rr < 4; ++rr) {
            int o = mq * 16 + quad * 4 + rr;
            out[(((size_t)b * COUT + o) * H_N + y) * W_N + x] = acc[nt][rr] + bias[o];
        }
    }
}

// ---- fallback scalar kernel (used only if ws too small) ----
__global__ __launch_bounds__(256)
void conv25d(const float* __restrict__ inp, const float* __restrict__ depth,
             const float* __restrict__ wsrc, const float* __restrict__ bias,
             const int* __restrict__ fptr, float* __restrict__ out) {
    int bid = blockIdx.x;
    int xt  = bid & 3;
    int y   = (bid >> 2) & (H_N - 1);
    int b   = bid >> 9;
    int o   = threadIdx.x & 63;
    int q   = threadIdx.x >> 6;
    int x0  = xt * 32 + q * 8;
    double fd = (double)(*fptr);
    float acc[8];
    float bv = bias[o];
#pragma unroll
    for (int i = 0; i < 8; ++i) acc[i] = bv;
    const float* dcen = depth + ((size_t)b * H_N + y) * W_N;
    float d0[8];
#pragma unroll
    for (int i = 0; i < 8; ++i) d0[i] = dcen[x0 + i];
    for (int t = 0; t < 9; ++t) {
        int dy = t / 3 - 1, dx = t % 3 - 1;
        int yy = y + dy;
        if (yy < 0 || yy >= H_N) continue;
        const float* drow = depth + ((size_t)b * H_N + yy) * W_N;
        int hsel[8];
#pragma unroll
        for (int i = 0; i < 8; ++i) {
            int xx = x0 + i + dx;
            int h = -1;
            if (xx >= 0 && xx < W_N) {
                double dd = (double)d0[i];
                double s0 = dd / fd;
                if (s0 > 0.0) {
                    double u = ((double)drow[xx] - dd) / s0 + 1.5;
                    double uf = floor(u);
                    if (uf >= 0.0 && uf <= 2.0) h = (int)uf;
                }
            }
            hsel[i] = h;
        }
        const float* irow = inp + ((size_t)b * CIN * H_N + yy) * W_N;
        for (int c = 0; c < CIN; ++c) {
            const float* wb = wsrc + ((size_t)o * CIN + c) * 9 + t;
            float w0 = wb[0], w1 = wb[(size_t)COUT * CIN * 9], w2 = wb[2 * (size_t)COUT * CIN * 9];
            const float* ir = irow + (size_t)c * H_N * W_N;
#pragma unroll
            for (int i = 0; i < 8; ++i) {
                int h = hsel[i];
                if (h >= 0) {
                    float wv = (h == 0) ? w0 : ((h == 1) ? w1 : w2);
                    acc[i] = fmaf(ir[x0 + i + dx], wv, acc[i]);
                }
            }
        }
    }
    float* orow = out + (((size_t)b * COUT + o) * H_N + y) * W_N;
#pragma unroll
    for (int i = 0; i < 8; ++i) orow[x0 + i] = acc[i];
}

extern "C" void kernel_launch(void* const* d_in, const int* in_sizes, int n_in,
                              void* d_out, int out_size, void* d_ws, size_t ws_size,
                              hipStream_t stream) {
    const float* inp   = (const float*)d_in[0];
    const float* depth = (const float*)d_in[1];
    const float* w     = (const float*)d_in[2];
    const float* bias  = (const float*)d_in[3];
    const int*   f     = (const int*)d_in[4];
    float* out = (float*)d_out;

    if (ws_size >= WA_BYTES) {
        _Float16* wa = (_Float16*)d_ws;
        wprep<<<NSTEP, 256, 0, stream>>>(w, wa);
        conv_mfma<<<B_N * H_N * 2, 256, 0, stream>>>(inp, depth, wa, bias, f, out);
    } else {
        conv25d<<<B_N * H_N * (W_N / 32), 256, 0, stream>>>(inp, depth, w, bias, f, out);
    }
}

// Round 8
// 96.701 us; speedup vs baseline: 1.1442x; 1.0290x over previous
//
#include <hip/hip_runtime.h>
#include <math.h>

#define B_N  4
#define CIN  64
#define COUT 64
#define H_N  128
#define W_N  128

typedef _Float16 half8 __attribute__((ext_vector_type(8)));
typedef float    f32x4 __attribute__((ext_vector_type(4)));

#define KTOT   1728              // 27 groups (t*3+h) * 64 c
#define NSTEP  54                // KTOT / 32
#define WA_BYTES ((size_t)NSTEP * 4 * 64 * 8 * 2)   // 221184 B

// ---- pack weights (3,Cout,Cin,3,3) fp32 -> f16 in MFMA A-fragment order ----
// A-fragment for K-step s, m-tile mt, lane l: 8 f16 = A[m=mt*16+(l&15)][k=s*32+(l>>4)*8+j]
// k -> (t,h,c): g=k>>6, c=k&63, t=g/3, h=g%3
__global__ void wprep(const float* __restrict__ w, _Float16* __restrict__ wa) {
    int idx = blockIdx.x * 256 + threadIdx.x;        // (s, mt, lane)
    if (idx >= NSTEP * 4 * 64) return;
    int lane = idx & 63;
    int mt   = (idx >> 6) & 3;
    int s    = idx >> 8;
    int m    = mt * 16 + (lane & 15);
    int kl0  = (lane >> 4) * 8;
    _Float16 v[8];
#pragma unroll
    for (int j = 0; j < 8; ++j) {
        int k = s * 32 + kl0 + j;
        int g = k >> 6;
        int c = k & 63;
        int t = g / 3;
        int h = g % 3;
        v[j] = (_Float16)w[(((size_t)(h * COUT) + m) * CIN + c) * 9 + t];
    }
    *(int4*)&wa[(size_t)idx * 8] = *(int4*)v;
}

// XOR chunk-swizzle LDS layout: line = 64 halfs (128 B) per (dy, x);
// logical 16-B chunk lc of line xi lives at halfs offset xi*64 + ((lc ^ (xi&7))*8).
#define XS_LINE 64
#define XS_ROW  (130 * XS_LINE)          // 8320 halfs per dy-plane (halo+128+halo)

// R9: N-per-wave doubled. Block = full row (128 px x 64 Cout), 512 blocks;
// wave = m-quarter (16 Cout) x 128 px (8 n-tiles). Halves the per-CU
// A-fragment register-fill (the largest reducible component: waves/CU x 55KB),
// doubles MFMA per A-fragment. B-read totals and staging totals unchanged.
// Row-pipelined staging kept from R8; zero pads written once (never change).
// Accumulation order (t, h, kk) per output element: bitwise identical.
__global__ __launch_bounds__(256, 2)
void conv_mfma(const float* __restrict__ inp, const float* __restrict__ depth,
               const _Float16* __restrict__ wa, const float* __restrict__ bias,
               const int* __restrict__ fptr, float* __restrict__ out) {
    __shared__ _Float16 Xs[3 * XS_ROW];              // 49920 B
    __shared__ unsigned hLds[128];                   // per-pixel h-selection packs

    int bid  = blockIdx.x;
    int y    = bid & (H_N - 1);
    int b    = bid >> 7;
    int tid  = threadIdx.x;
    int lane = tid & 63;
    int mq   = tid >> 6;                             // wave id = m-quarter
    int ln15 = lane & 15;
    int quad = lane >> 4;

    // staging thread roles (fixed for all rows): 128 px x 2 c-halves
    int xl    = tid & 127;                           // x position
    int chalf = tid >> 7;                            // c in [chalf*32, chalf*32+32)
    int xi    = xl + 1;
    int key   = xi & 7;

    const size_t HW = (size_t)H_N * W_N;

#define LOAD_ROW(dyi, buf) {                                                  \
        int yy_ = y + (dyi) - 1;                                              \
        if (yy_ >= 0 && yy_ < H_N) {                                          \
            const float* src_ = inp + (((size_t)b * CIN + chalf * 32) * H_N + yy_) * W_N + xl; \
            _Pragma("unroll")                                                 \
            for (int cc = 0; cc < 32; ++cc) buf[cc] = src_[(size_t)cc * HW];  \
        } else {                                                              \
            _Pragma("unroll")                                                 \
            for (int cc = 0; cc < 32; ++cc) buf[cc] = 0.f;                    \
        }                                                                     \
    }

#define WRITE_ROW(dyi, buf) {                                                 \
        _Float16 hb_[32];                                                     \
        _Pragma("unroll")                                                     \
        for (int cc = 0; cc < 32; ++cc) hb_[cc] = (_Float16)buf[cc];          \
        _Float16* dst_ = &Xs[(dyi) * XS_ROW + xi * XS_LINE];                  \
        _Pragma("unroll")                                                     \
        for (int k = 0; k < 4; ++k)                                           \
            *(int4*)&dst_[((chalf * 4 + k) ^ key) * 8] = *(int4*)&hb_[k * 8]; \
    }

    // ---- prologue: stage row 0; zero pads (once); A(0) preload; h-pack ----
    const half8* wa8 = (const half8*)wa;   // frag index: (t*24 + j*4 + mt)*64 + lane
    half8 Abuf[2][6];

    float rbuf[32];
    LOAD_ROW(0, rbuf);

    {
        const half8* bA = wa8 + (size_t)mq * 64 + lane;
#pragma unroll
        for (int j = 0; j < 6; ++j) Abuf[0][j] = bA[(size_t)j * 4 * 64];
    }

    // zero pad lines xi=0 (x=-1) and xi=129 (x=128) for ALL 3 planes, once.
    if (tid < 48) {
        int dyi = tid / 16;
        int rem = tid % 16;
        int xz  = (rem >= 8) ? 129 : 0;
        int k8  = rem & 7;
        int4 z  = {0, 0, 0, 0};
        *(int4*)&Xs[dyi * XS_ROW + xz * XS_LINE + k8 * 8] = z;
    }

    // h-selection packs: one pixel per thread (waves 0-1), LDS broadcast
    // u = (dw - d0)*(f/d0) + 1.5; dd==0 -> inv=inf/nan -> h=-1 (matches exact path)
    if (tid < 128) {
        int x = tid;
        double fd  = (double)(*fptr);
        float  d0f = depth[((size_t)b * H_N + y) * W_N + x];
        double dd  = (double)d0f;
        double inv = fd / dd;
        bool   pos = (inv > 0.0);
        unsigned pk = 0;
        for (int t = 0; t < 9; ++t) {
            int dy = t / 3 - 1, dx = t % 3 - 1;
            int yy = y + dy, xx = x + dx;
            float dwf = (yy >= 0 && yy < H_N && xx >= 0 && xx < W_N)
                        ? depth[((size_t)b * H_N + yy) * W_N + xx] : 0.f;
            int h = -1;
            if (pos) {
                double u  = ((double)dwf - dd) * inv + 1.5;
                double uf = floor(u);
                if (uf >= 0.0 && uf <= 2.0) h = (int)uf;
            }
            pk |= (unsigned)(h + 1) << (2 * t);
        }
        hLds[tid] = pk;
    }

    WRITE_ROW(0, rbuf);
    __syncthreads();

    unsigned hpk[8];
#pragma unroll
    for (int nt = 0; nt < 8; ++nt) hpk[nt] = hLds[nt * 16 + ln15];

    // ---- main loop: 3 phases (one dy-row each), 3 taps per phase ----
    f32x4 acc[8];                                    // [nt]
#pragma unroll
    for (int nt = 0; nt < 8; ++nt) acc[nt] = (f32x4){0.f, 0.f, 0.f, 0.f};

    half8 z8 = {(_Float16)0.f, (_Float16)0.f, (_Float16)0.f, (_Float16)0.f,
                (_Float16)0.f, (_Float16)0.f, (_Float16)0.f, (_Float16)0.f};

#pragma unroll
    for (int r = 0; r < 3; ++r) {
        // issue next row's global loads (land during this phase's MFMAs)
        float nbuf[32];
        if (r < 2) LOAD_ROW(r + 1, nbuf);

#pragma unroll
        for (int dxl = 0; dxl < 3; ++dxl) {
            int t  = r * 3 + dxl;
            int dx = dxl - 1;

            // B(t): 16 ds_read_b128 from plane r
            half8 bb[16];
#pragma unroll
            for (int nt = 0; nt < 8; ++nt) {
                int xs = nt * 16 + ln15 + dx + 1;    // in [0, 129]
                int k2 = xs & 7;
                int ba = r * XS_ROW + xs * XS_LINE;
                bb[nt * 2 + 0] = *(const half8*)&Xs[ba + ((quad    ) ^ k2) * 8];
                bb[nt * 2 + 1] = *(const half8*)&Xs[ba + ((quad + 4) ^ k2) * 8];
            }

            // A(t+1) prefetch into the other register buffer
            if (t < 8) {
                const half8* bA = wa8 + ((size_t)(t + 1) * 24 + mq) * 64 + lane;
#pragma unroll
                for (int j = 0; j < 6; ++j) Abuf[(t + 1) & 1][j] = bA[(size_t)j * 4 * 64];
            }

            int hb[8];
#pragma unroll
            for (int nt = 0; nt < 8; ++nt) hb[nt] = (hpk[nt] >> (2 * t)) & 3;

            // accumulation order per output element identical to R5-R8: (h, kk) asc
#pragma unroll
            for (int h = 0; h < 3; ++h) {
#pragma unroll
                for (int kk = 0; kk < 2; ++kk) {
                    int j = h * 2 + kk;
#pragma unroll
                    for (int nt = 0; nt < 8; ++nt) {
                        half8 c = (hb[nt] == h + 1) ? bb[nt * 2 + kk] : z8;
                        acc[nt] = __builtin_amdgcn_mfma_f32_16x16x32_f16(Abuf[t & 1][j], c, acc[nt], 0, 0, 0);
                    }
                }
            }
        }

        if (r < 2) {
            WRITE_ROW(r + 1, nbuf);
            __syncthreads();                         // row r+1 visible before its taps
        }
    }
#undef LOAD_ROW
#undef WRITE_ROW

    // ---- epilogue: D[m=o: quad*4+r][n=pixel: lane&15] + bias ----
#pragma unroll
    for (int nt = 0; nt < 8; ++nt) {
        int x = nt * 16 + ln15;
#pragma unroll
        for (int rr = 0; rr < 4; ++rr) {
            int o = mq * 16 + quad * 4 + rr;
            out[(((size_t)b * COUT + o) * H_N + y) * W_N + x] = acc[nt][rr] + bias[o];
        }
    }
}

// ---- fallback scalar kernel (used only if ws too small) ----
__global__ __launch_bounds__(256)
void conv25d(const float* __restrict__ inp, const float* __restrict__ depth,
             const float* __restrict__ wsrc, const float* __restrict__ bias,
             const int* __restrict__ fptr, float* __restrict__ out) {
    int bid = blockIdx.x;
    int xt  = bid & 3;
    int y   = (bid >> 2) & (H_N - 1);
    int b   = bid >> 9;
    int o   = threadIdx.x & 63;
    int q   = threadIdx.x >> 6;
    int x0  = xt * 32 + q * 8;
    double fd = (double)(*fptr);
    float acc[8];
    float bv = bias[o];
#pragma unroll
    for (int i = 0; i < 8; ++i) acc[i] = bv;
    const float* dcen = depth + ((size_t)b * H_N + y) * W_N;
    float d0[8];
#pragma unroll
    for (int i = 0; i < 8; ++i) d0[i] = dcen[x0 + i];
    for (int t = 0; t < 9; ++t) {
        int dy = t / 3 - 1, dx = t % 3 - 1;
        int yy = y + dy;
        if (yy < 0 || yy >= H_N) continue;
        const float* drow = depth + ((size_t)b * H_N + yy) * W_N;
        int hsel[8];
#pragma unroll
        for (int i = 0; i < 8; ++i) {
            int xx = x0 + i + dx;
            int h = -1;
            if (xx >= 0 && xx < W_N) {
                double dd = (double)d0[i];
                double s0 = dd / fd;
                if (s0 > 0.0) {
                    double u = ((double)drow[xx] - dd) / s0 + 1.5;
                    double uf = floor(u);
                    if (uf >= 0.0 && uf <= 2.0) h = (int)uf;
                }
            }
            hsel[i] = h;
        }
        const float* irow = inp + ((size_t)b * CIN * H_N + yy) * W_N;
        for (int c = 0; c < CIN; ++c) {
            const float* wb = wsrc + ((size_t)o * CIN + c) * 9 + t;
            float w0 = wb[0], w1 = wb[(size_t)COUT * CIN * 9], w2 = wb[2 * (size_t)COUT * CIN * 9];
            const float* ir = irow + (size_t)c * H_N * W_N;
#pragma unroll
            for (int i = 0; i < 8; ++i) {
                int h = hsel[i];
                if (h >= 0) {
                    float wv = (h == 0) ? w0 : ((h == 1) ? w1 : w2);
                    acc[i] = fmaf(ir[x0 + i + dx], wv, acc[i]);
                }
            }
        }
    }
    float* orow = out + (((size_t)b * COUT + o) * H_N + y) * W_N;
#pragma unroll
    for (int i = 0; i < 8; ++i) orow[x0 + i] = acc[i];
}

extern "C" void kernel_launch(void* const* d_in, const int* in_sizes, int n_in,
                              void* d_out, int out_size, void* d_ws, size_t ws_size,
                              hipStream_t stream) {
    const float* inp   = (const float*)d_in[0];
    const float* depth = (const float*)d_in[1];
    const float* w     = (const float*)d_in[2];
    const float* bias  = (const float*)d_in[3];
    const int*   f     = (const int*)d_in[4];
    float* out = (float*)d_out;

    if (ws_size >= WA_BYTES) {
        _Float16* wa = (_Float16*)d_ws;
        wprep<<<NSTEP, 256, 0, stream>>>(w, wa);
        conv_mfma<<<B_N * H_N, 256, 0, stream>>>(inp, depth, wa, bias, f, out);
    } else {
        conv25d<<<B_N * H_N * (W_N / 32), 256, 0, stream>>>(inp, depth, w, bias, f, out);
    }
}